// Round 3
// baseline (520.020 us; speedup 1.0000x reference)
//
#include <hip/hip_runtime.h>
#include <hip/hip_fp16.h>

// KbInterpForw: table-based KB NUFFT interpolation, forward.
// x: (2,16,2,512,512) f32, om: (2,2,262144) f32, tables: (2,6145) f32 each.
// out: (2,16,2,262144) f32.
//
// R3: fp16 grid records (64 B = 16 coils x complex), 4 lanes/point.
// Inner loop uses v_dot2_f32_f16 (fp16 pair products, exact f32 accumulate).
// __launch_bounds__(256,4) pins VGPR<=128 for 4 waves/SIMD.
// Transpose vectorized: dwordx4 reads over 4 cells.

#define KLEN      262144      // 2^18
#define GX        512
#define GY        512
#define NCOILS    16
#define NBATCH    2
#define TBL_LEN   6145        // 6*1024+1
#define TBL_CTR   3072
#define PLANE     (GX*GY)

typedef _Float16 half2_t __attribute__((ext_vector_type(2)));
struct alignas(16) H8 { half2_t h[4]; };   // 4 coils' (re,im) fp16 = 16 B

// ---------------------------------------------------------------------------
// Transpose+downconvert: x[b][c][ri][kx][ky] (f32 planes) ->
// xt[b][cell] = 16 x half2(re,im), 64 B/record.
// Thread = chunk q (coils 4q..4q+3) of 4 consecutive cells.
// Reads: 8 x dwordx4 (fully coalesced). Writes: 4 x 16 B.
// ---------------------------------------------------------------------------
__global__ __launch_bounds__(256) void transpose_fp16(
    const float* __restrict__ x, float4* __restrict__ xt)
{
    const int tid = blockIdx.x * blockDim.x + threadIdx.x;  // [0, NBATCH*PLANE)
    const int q   = tid & 3;
    const int g   = tid >> 2;          // group of 4 cells
    const int b   = g >> 16;           // PLANE/4 = 65536 groups per batch
    const int cell = (g & 65535) * 4;

    const float* xb = x + (size_t)b * NCOILS * 2 * PLANE + cell;

    H8 rec[4];
#pragma unroll
    for (int cc = 0; cc < 4; ++cc) {
        const int c = q * 4 + cc;
        const float4 r4 = *(const float4*)(xb + (size_t)(2 * c)     * PLANE);
        const float4 i4 = *(const float4*)(xb + (size_t)(2 * c + 1) * PLANE);
        rec[0].h[cc] = half2_t{(_Float16)r4.x, (_Float16)i4.x};
        rec[1].h[cc] = half2_t{(_Float16)r4.y, (_Float16)i4.y};
        rec[2].h[cc] = half2_t{(_Float16)r4.z, (_Float16)i4.z};
        rec[3].h[cc] = half2_t{(_Float16)r4.w, (_Float16)i4.w};
    }
#pragma unroll
    for (int i = 0; i < 4; ++i) {
        xt[(size_t)(b * PLANE + cell + i) * 4 + q] = *(const float4*)&rec[i];
    }
}

// ---------------------------------------------------------------------------
// Main interp: 4 lanes per k-point; lane owns coils 4*lane .. 4*lane+3.
// Per tap: one dwordx4 + 2 half2 packs + 8 v_dot2_f32_f16.
// ---------------------------------------------------------------------------
__global__ __launch_bounds__(256, 4) void interp_fp16(
    const float*  __restrict__ om,
    const float*  __restrict__ t0,
    const float*  __restrict__ t1,
    const float4* __restrict__ xt,
    float*        __restrict__ out)
{
    const int tid  = blockIdx.x * blockDim.x + threadIdx.x;
    const int lane = tid & 3;
    const int p    = tid >> 2;            // point index in [0, NBATCH*KLEN)
    const int b    = p >> 18;             // KLEN = 2^18
    const int m    = p & (KLEN - 1);

    const float om0 = om[(size_t)(b * 2 + 0) * KLEN + m];
    const float om1 = om[(size_t)(b * 2 + 1) * KLEN + m];

    const float TWO_PI = 6.2831853071795864769f;
    const float tm0 = (om0 * 512.0f) / TWO_PI;
    const float tm1 = (om1 * 512.0f) / TWO_PI;

    const float koff0 = 1.0f + floorf(tm0 - 3.0f);
    const float koff1 = 1.0f + floorf(tm1 - 3.0f);
    const int   k0    = (int)koff0;
    const int   k1    = (int)koff1;

    float c0r[6], c0i[6], c1r[6], c1i[6];
    int   coff[6];
#pragma unroll
    for (int j = 0; j < 6; ++j) {
        const float g0 = koff0 + (float)j;
        const int   d0 = (int)rintf((tm0 - g0) * 1024.0f) + TBL_CTR;
        c0r[j] = t0[d0];
        c0i[j] = t0[TBL_LEN + d0];
        const float g1 = koff1 + (float)j;
        const int   d1 = (int)rintf((tm1 - g1) * 1024.0f) + TBL_CTR;
        c1r[j] = t1[d1];
        c1i[j] = t1[TBL_LEN + d1];
        coff[j] = ((k1 + j) & 511) << 2;   // chunk offset within row
    }

    const float4* rec = xt + ((size_t)b << 20);   // b * PLANE * 4 chunks
    float acr[4] = {0.f, 0.f, 0.f, 0.f};
    float aci[4] = {0.f, 0.f, 0.f, 0.f};
#pragma unroll
    for (int j0 = 0; j0 < 6; ++j0) {
        const int roff = (k0 + j0) & 511;
        const float4* rowp = rec + ((size_t)roff << 11) + lane;  // *512*4
        const float ar = c0r[j0], ai = c0i[j0];
#pragma unroll
        for (int j1 = 0; j1 < 6; ++j1) {
            const float br = c1r[j1], bi = c1i[j1];
            const float cr = ar * br - ai * bi;
            const float ci = ar * bi + ai * br;
            const half2_t p1 = {(_Float16)cr, (_Float16)(-ci)}; // for real acc
            const half2_t p2 = {(_Float16)ci, (_Float16)cr};    // for imag acc
            const float4 raw = rowp[coff[j1]];
            const H8 v = *(const H8*)&raw;
#pragma unroll
            for (int cc = 0; cc < 4; ++cc) {
                acr[cc] = __builtin_amdgcn_fdot2(v.h[cc], p1, acr[cc], false);
                aci[cc] = __builtin_amdgcn_fdot2(v.h[cc], p2, aci[cc], false);
            }
        }
    }

    // phase twist: exp(i * (om0+om1)*128)
    const float ph = om0 * 128.0f + om1 * 128.0f;
    const float s = sinf(ph), c = cosf(ph);

#pragma unroll
    for (int cc = 0; cc < 4; ++cc) {
        const float yr = acr[cc] * c - aci[cc] * s;
        const float yi = acr[cc] * s + aci[cc] * c;
        const int coil = lane * 4 + cc;
        const size_t ob = ((size_t)(b * NCOILS + coil) * 2) * KLEN + m;
        out[ob]        = yr;
        out[ob + KLEN] = yi;
    }
}

// ---------------------------------------------------------------------------
// Fallback (no workspace): one thread per point, scalar gathers from original
// layout. Correct but slow; only used if ws_size is too small.
// ---------------------------------------------------------------------------
__global__ __launch_bounds__(256) void interp_fallback(
    const float* __restrict__ om,
    const float* __restrict__ t0,
    const float* __restrict__ t1,
    const float* __restrict__ x,
    float*       __restrict__ out)
{
    const int p = blockIdx.x * blockDim.x + threadIdx.x;
    const int b = p >> 18;
    const int m = p & (KLEN - 1);

    const float om0 = om[(size_t)(b * 2 + 0) * KLEN + m];
    const float om1 = om[(size_t)(b * 2 + 1) * KLEN + m];
    const float TWO_PI = 6.2831853071795864769f;
    const float tm0 = (om0 * 512.0f) / TWO_PI;
    const float tm1 = (om1 * 512.0f) / TWO_PI;
    const float koff0 = 1.0f + floorf(tm0 - 3.0f);
    const float koff1 = 1.0f + floorf(tm1 - 3.0f);
    const int k0 = (int)koff0, k1 = (int)koff1;

    float c0r[6], c0i[6], c1r[6], c1i[6];
    int roff[6], coff[6];
#pragma unroll
    for (int j = 0; j < 6; ++j) {
        const float g0 = koff0 + (float)j;
        const int d0 = (int)rintf((tm0 - g0) * 1024.0f) + TBL_CTR;
        c0r[j] = t0[d0];
        c0i[j] = t0[TBL_LEN + d0];
        const float g1 = koff1 + (float)j;
        const int d1 = (int)rintf((tm1 - g1) * 1024.0f) + TBL_CTR;
        c1r[j] = t1[d1];
        c1i[j] = t1[TBL_LEN + d1];
        roff[j] = (k0 + j) & 511;
        coff[j] = (k1 + j) & 511;
    }

    float accr[NCOILS], acci[NCOILS];
#pragma unroll
    for (int c = 0; c < NCOILS; ++c) { accr[c] = 0.f; acci[c] = 0.f; }

    const float* xb = x + (size_t)b * NCOILS * 2 * PLANE;
#pragma unroll
    for (int j0 = 0; j0 < 6; ++j0) {
        const float ar = c0r[j0], ai = c0i[j0];
        const int rb = roff[j0] * GY;
#pragma unroll
        for (int j1 = 0; j1 < 6; ++j1) {
            const float br = c1r[j1], bi = c1i[j1];
            const float cr = ar * br - ai * bi;
            const float ci = ar * bi + ai * br;
            const int ai_idx = rb + coff[j1];
#pragma unroll
            for (int c = 0; c < NCOILS; ++c) {
                const float dr = xb[(size_t)c * (2 * PLANE) + ai_idx];
                const float di = xb[(size_t)c * (2 * PLANE) + PLANE + ai_idx];
                accr[c] += cr * dr - ci * di;
                acci[c] += cr * di + ci * dr;
            }
        }
    }

    const float ph = om0 * 128.0f + om1 * 128.0f;
    const float s = sinf(ph), c = cosf(ph);
#pragma unroll
    for (int cc = 0; cc < NCOILS; ++cc) {
        const float yr = accr[cc] * c - acci[cc] * s;
        const float yi = accr[cc] * s + acci[cc] * c;
        size_t ob = ((size_t)(b * NCOILS + cc) * 2) * KLEN + m;
        out[ob]        = yr;
        out[ob + KLEN] = yi;
    }
}

extern "C" void kernel_launch(void* const* d_in, const int* in_sizes, int n_in,
                              void* d_out, int out_size, void* d_ws, size_t ws_size,
                              hipStream_t stream)
{
    const float* x  = (const float*)d_in[0];
    const float* om = (const float*)d_in[1];
    const float* t0 = (const float*)d_in[2];
    const float* t1 = (const float*)d_in[3];
    float* out = (float*)d_out;

    // fp16 records: 2 batches * 512*512 cells * 64 B = 33.5 MB
    const size_t xt_bytes = (size_t)NBATCH * PLANE * NCOILS * 2 * sizeof(__half);

    if (ws_size >= xt_bytes) {
        float4* xt = (float4*)d_ws;
        {
            const int total = NBATCH * PLANE;       // thread = 4 cells x 4 coils
            transpose_fp16<<<total / 256, 256, 0, stream>>>(x, xt);
        }
        {
            const int total = NBATCH * KLEN * 4;    // 4 lanes per point
            interp_fp16<<<total / 256, 256, 0, stream>>>(om, t0, t1, xt, out);
        }
    } else {
        const int total = NBATCH * KLEN;
        interp_fallback<<<total / 256, 256, 0, stream>>>(om, t0, t1, x, out);
    }
}

// Round 4
// 406.010 us; speedup vs baseline: 1.2808x; 1.2808x over previous
//
#include <hip/hip_runtime.h>
#include <hip/hip_fp16.h>

// KbInterpForw: table-based KB NUFFT interpolation, forward.
// x: (2,16,2,512,512) f32, om: (2,2,262144) f32, tables: (2,6145) f32 each.
// out: (2,16,2,262144) f32.
//
// R4: spatially tile-sorted gathers.
//   1. transpose grid -> fp16 records (64 B = 16 coils x complex), coalesced
//   2. counting sort of points by 16x16 grid tile (2048 bins)
//   3. interp in sorted order (L1/L2-local gathers), fp16 output per point
//   4. unsort pass -> final layout, coalesced writes
// No __launch_bounds__ min-waves (R3: it forced VGPR=64 -> 710 MB spill).

#define KLEN      262144      // 2^18
#define GX        512
#define GY        512
#define NCOILS    16
#define NBATCH    2
#define TBL_LEN   6145        // 6*1024+1
#define TBL_CTR   3072
#define PLANE     (GX*GY)
#define NPTS      (NBATCH*KLEN)
#define NBINS     2048        // NBATCH * 32*32 tiles

typedef _Float16 half2_t __attribute__((ext_vector_type(2)));
struct alignas(16) H8 { half2_t h[4]; };   // 4 coils' (re,im) fp16 = 16 B

// ---------------------------------------------------------------------------
// ws layout (bytes)
// ---------------------------------------------------------------------------
#define WS_XT      0                          // 33554432  fp16 grid records
#define WS_OSORT   33554432                   // 33554432  fp16 sorted outputs
#define WS_SORTED  67108864                   //  2097152  u32 point id per pos
#define WS_INV     69206016                   //  2097152  u32 pos per point id
#define WS_SOM     71303168                   //  4194304  float2 om per pos
#define WS_HIST    75497472                   //     8192
#define WS_CURSOR  75505664                   //     8192
#define WS_TOTAL   75513856

__device__ inline int point_bin(float om0, float om1)
{
    const float TWO_PI = 6.2831853071795864769f;
    const float tm0 = (om0 * 512.0f) / TWO_PI;
    const float tm1 = (om1 * 512.0f) / TWO_PI;
    const int cx = ((int)floorf(tm0)) & 511;
    const int cy = ((int)floorf(tm1)) & 511;
    return ((cx >> 4) << 5) | (cy >> 4);      // [0, 1024)
}

// ---------------------------------------------------------------------------
// Transpose+downconvert. Thread handles 4-coil chunk q of 4 consecutive cells.
// q is constant within a wave (bits 16..17 of r) -> every read instruction is
// a fully coalesced float4 stream over cells.
// ---------------------------------------------------------------------------
__global__ __launch_bounds__(256) void transpose_fp16(
    const float* __restrict__ x, float4* __restrict__ xt)
{
    const int tid = blockIdx.x * blockDim.x + threadIdx.x;  // [0, NBATCH*PLANE)
    const int b   = tid >> 18;
    const int r   = tid & (PLANE - 1);
    const int q   = r >> 16;            // 4-coil chunk, wave-uniform
    const int cg  = r & 65535;          // cell group (4 cells)
    const int cell = cg * 4;

    const float* xb = x + (size_t)b * NCOILS * 2 * PLANE + cell;

    H8 rec[4];
#pragma unroll
    for (int cc = 0; cc < 4; ++cc) {
        const int c = q * 4 + cc;
        const float4 r4 = *(const float4*)(xb + (size_t)(2 * c)     * PLANE);
        const float4 i4 = *(const float4*)(xb + (size_t)(2 * c + 1) * PLANE);
        rec[0].h[cc] = half2_t{(_Float16)r4.x, (_Float16)i4.x};
        rec[1].h[cc] = half2_t{(_Float16)r4.y, (_Float16)i4.y};
        rec[2].h[cc] = half2_t{(_Float16)r4.z, (_Float16)i4.z};
        rec[3].h[cc] = half2_t{(_Float16)r4.w, (_Float16)i4.w};
    }
#pragma unroll
    for (int i = 0; i < 4; ++i) {
        xt[(size_t)(b * PLANE + cell + i) * 4 + q] = *(const float4*)&rec[i];
    }
}

// ---------------------------------------------------------------------------
// Sort passes
// ---------------------------------------------------------------------------
__global__ __launch_bounds__(256) void zero_hist(unsigned* __restrict__ hist)
{
    const int i = blockIdx.x * blockDim.x + threadIdx.x;
    if (i < NBINS) hist[i] = 0u;
}

__global__ __launch_bounds__(256) void hist_kernel(
    const float* __restrict__ om, unsigned* __restrict__ hist)
{
    const int id = blockIdx.x * blockDim.x + threadIdx.x;   // [0, NPTS)
    const int b = id >> 18, m = id & (KLEN - 1);
    const float om0 = om[(size_t)(b * 2 + 0) * KLEN + m];
    const float om1 = om[(size_t)(b * 2 + 1) * KLEN + m];
    const int g = (b << 10) | point_bin(om0, om1);
    atomicAdd(&hist[g], 1u);
}

__global__ __launch_bounds__(256) void scan_kernel(
    const unsigned* __restrict__ hist, unsigned* __restrict__ cursor)
{
    __shared__ unsigned partial[256];
    const int t = threadIdx.x;
    unsigned v[8];
    unsigned s = 0;
#pragma unroll
    for (int i = 0; i < 8; ++i) { v[i] = hist[t * 8 + i]; s += v[i]; }
    partial[t] = s;
    __syncthreads();
    for (int d = 1; d < 256; d <<= 1) {
        unsigned x = (t >= d) ? partial[t - d] : 0u;
        __syncthreads();
        partial[t] += x;
        __syncthreads();
    }
    unsigned base = (t > 0) ? partial[t - 1] : 0u;   // exclusive
#pragma unroll
    for (int i = 0; i < 8; ++i) { cursor[t * 8 + i] = base; base += v[i]; }
}

__global__ __launch_bounds__(256) void scatter_kernel(
    const float* __restrict__ om, unsigned* __restrict__ cursor,
    unsigned* __restrict__ sorted, unsigned* __restrict__ inv,
    float2* __restrict__ som)
{
    const int id = blockIdx.x * blockDim.x + threadIdx.x;   // [0, NPTS)
    const int b = id >> 18, m = id & (KLEN - 1);
    const float om0 = om[(size_t)(b * 2 + 0) * KLEN + m];
    const float om1 = om[(size_t)(b * 2 + 1) * KLEN + m];
    const int g = (b << 10) | point_bin(om0, om1);
    const unsigned pos = atomicAdd(&cursor[g], 1u);
    sorted[pos] = (unsigned)id;
    inv[id]     = pos;
    som[pos]    = make_float2(om0, om1);
}

// ---------------------------------------------------------------------------
// Main interp over sorted positions: 4 lanes per point, lane owns 4 coils.
// Gathers are tile-local (16x16 bins -> ~28 KB neighborhood). Output written
// coalesced as fp16 record per sorted position.
// ---------------------------------------------------------------------------
__global__ __launch_bounds__(256) void interp_sorted(
    const unsigned* __restrict__ sorted,
    const float2*   __restrict__ som,
    const float*    __restrict__ t0,
    const float*    __restrict__ t1,
    const float4*   __restrict__ xt,
    float4*         __restrict__ osort)
{
    const int tid  = blockIdx.x * blockDim.x + threadIdx.x;
    const int lane = tid & 3;
    const int pos  = tid >> 2;            // sorted position in [0, NPTS)

    const unsigned id = sorted[pos];
    const int b = (int)(id >> 18);
    const float2 o = som[pos];
    const float om0 = o.x, om1 = o.y;

    const float TWO_PI = 6.2831853071795864769f;
    const float tm0 = (om0 * 512.0f) / TWO_PI;
    const float tm1 = (om1 * 512.0f) / TWO_PI;

    const float koff0 = 1.0f + floorf(tm0 - 3.0f);
    const float koff1 = 1.0f + floorf(tm1 - 3.0f);
    const int   k0    = (int)koff0;
    const int   k1    = (int)koff1;

    float c0r[6], c0i[6], c1r[6], c1i[6];
    int   coff[6];
#pragma unroll
    for (int j = 0; j < 6; ++j) {
        const float g0 = koff0 + (float)j;
        const int   d0 = (int)rintf((tm0 - g0) * 1024.0f) + TBL_CTR;
        c0r[j] = t0[d0];
        c0i[j] = t0[TBL_LEN + d0];
        const float g1 = koff1 + (float)j;
        const int   d1 = (int)rintf((tm1 - g1) * 1024.0f) + TBL_CTR;
        c1r[j] = t1[d1];
        c1i[j] = t1[TBL_LEN + d1];
        coff[j] = ((k1 + j) & 511) << 2;   // chunk offset within row
    }

    const float4* rec = xt + ((size_t)b << 20);   // b * PLANE * 4 chunks
    float acr[4] = {0.f, 0.f, 0.f, 0.f};
    float aci[4] = {0.f, 0.f, 0.f, 0.f};
#pragma unroll
    for (int j0 = 0; j0 < 6; ++j0) {
        const int roff = (k0 + j0) & 511;
        const float4* rowp = rec + ((size_t)roff << 11) + lane;  // *512*4
        const float ar = c0r[j0], ai = c0i[j0];
#pragma unroll
        for (int j1 = 0; j1 < 6; ++j1) {
            const float br = c1r[j1], bi = c1i[j1];
            const float cr = ar * br - ai * bi;
            const float ci = ar * bi + ai * br;
            const half2_t p1 = {(_Float16)cr, (_Float16)(-ci)}; // real acc
            const half2_t p2 = {(_Float16)ci, (_Float16)cr};    // imag acc
            const float4 raw = rowp[coff[j1]];
            const H8 v = *(const H8*)&raw;
#pragma unroll
            for (int cc = 0; cc < 4; ++cc) {
                acr[cc] = __builtin_amdgcn_fdot2(v.h[cc], p1, acr[cc], false);
                aci[cc] = __builtin_amdgcn_fdot2(v.h[cc], p2, aci[cc], false);
            }
        }
    }

    // phase twist: exp(i * (om0+om1)*128)
    const float ph = om0 * 128.0f + om1 * 128.0f;
    const float s = sinf(ph), c = cosf(ph);

    H8 outrec;
#pragma unroll
    for (int cc = 0; cc < 4; ++cc) {
        const float yr = acr[cc] * c - aci[cc] * s;
        const float yi = acr[cc] * s + aci[cc] * c;
        outrec.h[cc] = half2_t{(_Float16)yr, (_Float16)yi};
    }
    osort[(size_t)pos * 4 + lane] = *(const float4*)&outrec;   // coalesced
}

// ---------------------------------------------------------------------------
// Unsort: thread per point id; gather its 64 B fp16 record from osort,
// scatter-free coalesced stores into final (b,c,ri,m) layout.
// ---------------------------------------------------------------------------
__global__ __launch_bounds__(256) void unsort_kernel(
    const unsigned* __restrict__ inv,
    const float4*   __restrict__ osort,
    float*          __restrict__ out)
{
    const int id = blockIdx.x * blockDim.x + threadIdx.x;   // [0, NPTS)
    const int b = id >> 18, m = id & (KLEN - 1);
    const unsigned pos = inv[id];
    const float4* rp = osort + (size_t)pos * 4;

    float4 raw[4];
#pragma unroll
    for (int q = 0; q < 4; ++q) raw[q] = rp[q];

    float* ob = out + (size_t)b * NCOILS * 2 * KLEN + m;
#pragma unroll
    for (int q = 0; q < 4; ++q) {
        const H8 v = *(const H8*)&raw[q];
#pragma unroll
        for (int cc = 0; cc < 4; ++cc) {
            const int coil = q * 4 + cc;
            const float re = (float)v.h[cc].x;
            const float im = (float)v.h[cc].y;
            ob[(size_t)(2 * coil)     * KLEN] = re;
            ob[(size_t)(2 * coil + 1) * KLEN] = im;
        }
    }
}

// ---------------------------------------------------------------------------
// Middle path (ws >= xt only): R2-style direct-order interp w/ fdot2.
// ---------------------------------------------------------------------------
__global__ __launch_bounds__(256) void interp_direct(
    const float*  __restrict__ om,
    const float*  __restrict__ t0,
    const float*  __restrict__ t1,
    const float4* __restrict__ xt,
    float*        __restrict__ out)
{
    const int tid  = blockIdx.x * blockDim.x + threadIdx.x;
    const int lane = tid & 3;
    const int p    = tid >> 2;
    const int b    = p >> 18;
    const int m    = p & (KLEN - 1);

    const float om0 = om[(size_t)(b * 2 + 0) * KLEN + m];
    const float om1 = om[(size_t)(b * 2 + 1) * KLEN + m];

    const float TWO_PI = 6.2831853071795864769f;
    const float tm0 = (om0 * 512.0f) / TWO_PI;
    const float tm1 = (om1 * 512.0f) / TWO_PI;
    const float koff0 = 1.0f + floorf(tm0 - 3.0f);
    const float koff1 = 1.0f + floorf(tm1 - 3.0f);
    const int k0 = (int)koff0, k1 = (int)koff1;

    float c0r[6], c0i[6], c1r[6], c1i[6];
    int coff[6];
#pragma unroll
    for (int j = 0; j < 6; ++j) {
        const float g0 = koff0 + (float)j;
        const int d0 = (int)rintf((tm0 - g0) * 1024.0f) + TBL_CTR;
        c0r[j] = t0[d0];
        c0i[j] = t0[TBL_LEN + d0];
        const float g1 = koff1 + (float)j;
        const int d1 = (int)rintf((tm1 - g1) * 1024.0f) + TBL_CTR;
        c1r[j] = t1[d1];
        c1i[j] = t1[TBL_LEN + d1];
        coff[j] = ((k1 + j) & 511) << 2;
    }

    const float4* rec = xt + ((size_t)b << 20);
    float acr[4] = {0.f, 0.f, 0.f, 0.f};
    float aci[4] = {0.f, 0.f, 0.f, 0.f};
#pragma unroll
    for (int j0 = 0; j0 < 6; ++j0) {
        const int roff = (k0 + j0) & 511;
        const float4* rowp = rec + ((size_t)roff << 11) + lane;
        const float ar = c0r[j0], ai = c0i[j0];
#pragma unroll
        for (int j1 = 0; j1 < 6; ++j1) {
            const float br = c1r[j1], bi = c1i[j1];
            const float cr = ar * br - ai * bi;
            const float ci = ar * bi + ai * br;
            const half2_t p1 = {(_Float16)cr, (_Float16)(-ci)};
            const half2_t p2 = {(_Float16)ci, (_Float16)cr};
            const float4 raw = rowp[coff[j1]];
            const H8 v = *(const H8*)&raw;
#pragma unroll
            for (int cc = 0; cc < 4; ++cc) {
                acr[cc] = __builtin_amdgcn_fdot2(v.h[cc], p1, acr[cc], false);
                aci[cc] = __builtin_amdgcn_fdot2(v.h[cc], p2, aci[cc], false);
            }
        }
    }

    const float ph = om0 * 128.0f + om1 * 128.0f;
    const float s = sinf(ph), c = cosf(ph);
#pragma unroll
    for (int cc = 0; cc < 4; ++cc) {
        const float yr = acr[cc] * c - aci[cc] * s;
        const float yi = acr[cc] * s + aci[cc] * c;
        const int coil = lane * 4 + cc;
        const size_t ob = ((size_t)(b * NCOILS + coil) * 2) * KLEN + m;
        out[ob]        = yr;
        out[ob + KLEN] = yi;
    }
}

// ---------------------------------------------------------------------------
// Fallback (tiny ws): one thread per point, original layout.
// ---------------------------------------------------------------------------
__global__ __launch_bounds__(256) void interp_fallback(
    const float* __restrict__ om,
    const float* __restrict__ t0,
    const float* __restrict__ t1,
    const float* __restrict__ x,
    float*       __restrict__ out)
{
    const int p = blockIdx.x * blockDim.x + threadIdx.x;
    const int b = p >> 18;
    const int m = p & (KLEN - 1);

    const float om0 = om[(size_t)(b * 2 + 0) * KLEN + m];
    const float om1 = om[(size_t)(b * 2 + 1) * KLEN + m];
    const float TWO_PI = 6.2831853071795864769f;
    const float tm0 = (om0 * 512.0f) / TWO_PI;
    const float tm1 = (om1 * 512.0f) / TWO_PI;
    const float koff0 = 1.0f + floorf(tm0 - 3.0f);
    const float koff1 = 1.0f + floorf(tm1 - 3.0f);
    const int k0 = (int)koff0, k1 = (int)koff1;

    float c0r[6], c0i[6], c1r[6], c1i[6];
    int roff[6], coff[6];
#pragma unroll
    for (int j = 0; j < 6; ++j) {
        const float g0 = koff0 + (float)j;
        const int d0 = (int)rintf((tm0 - g0) * 1024.0f) + TBL_CTR;
        c0r[j] = t0[d0];
        c0i[j] = t0[TBL_LEN + d0];
        const float g1 = koff1 + (float)j;
        const int d1 = (int)rintf((tm1 - g1) * 1024.0f) + TBL_CTR;
        c1r[j] = t1[d1];
        c1i[j] = t1[TBL_LEN + d1];
        roff[j] = (k0 + j) & 511;
        coff[j] = (k1 + j) & 511;
    }

    float accr[NCOILS], acci[NCOILS];
#pragma unroll
    for (int c = 0; c < NCOILS; ++c) { accr[c] = 0.f; acci[c] = 0.f; }

    const float* xb = x + (size_t)b * NCOILS * 2 * PLANE;
#pragma unroll
    for (int j0 = 0; j0 < 6; ++j0) {
        const float ar = c0r[j0], ai = c0i[j0];
        const int rb = roff[j0] * GY;
#pragma unroll
        for (int j1 = 0; j1 < 6; ++j1) {
            const float br = c1r[j1], bi = c1i[j1];
            const float cr = ar * br - ai * bi;
            const float ci = ar * bi + ai * br;
            const int ai_idx = rb + coff[j1];
#pragma unroll
            for (int c = 0; c < NCOILS; ++c) {
                const float dr = xb[(size_t)c * (2 * PLANE) + ai_idx];
                const float di = xb[(size_t)c * (2 * PLANE) + PLANE + ai_idx];
                accr[c] += cr * dr - ci * di;
                acci[c] += cr * di + ci * dr;
            }
        }
    }

    const float ph = om0 * 128.0f + om1 * 128.0f;
    const float s = sinf(ph), c = cosf(ph);
#pragma unroll
    for (int cc = 0; cc < NCOILS; ++cc) {
        const float yr = accr[cc] * c - acci[cc] * s;
        const float yi = accr[cc] * s + acci[cc] * c;
        size_t ob = ((size_t)(b * NCOILS + cc) * 2) * KLEN + m;
        out[ob]        = yr;
        out[ob + KLEN] = yi;
    }
}

extern "C" void kernel_launch(void* const* d_in, const int* in_sizes, int n_in,
                              void* d_out, int out_size, void* d_ws, size_t ws_size,
                              hipStream_t stream)
{
    const float* x  = (const float*)d_in[0];
    const float* om = (const float*)d_in[1];
    const float* t0 = (const float*)d_in[2];
    const float* t1 = (const float*)d_in[3];
    float* out = (float*)d_out;

    char* ws = (char*)d_ws;
    const size_t xt_bytes = (size_t)NBATCH * PLANE * NCOILS * 2 * sizeof(__half);

    if (ws_size >= (size_t)WS_TOTAL) {
        float4*   xt     = (float4*)(ws + WS_XT);
        float4*   osort  = (float4*)(ws + WS_OSORT);
        unsigned* sorted = (unsigned*)(ws + WS_SORTED);
        unsigned* inv    = (unsigned*)(ws + WS_INV);
        float2*   som    = (float2*)(ws + WS_SOM);
        unsigned* hist   = (unsigned*)(ws + WS_HIST);
        unsigned* cursor = (unsigned*)(ws + WS_CURSOR);

        transpose_fp16<<<NBATCH * PLANE / 256, 256, 0, stream>>>(x, xt);
        zero_hist<<<NBINS / 256, 256, 0, stream>>>(hist);
        hist_kernel<<<NPTS / 256, 256, 0, stream>>>(om, hist);
        scan_kernel<<<1, 256, 0, stream>>>(hist, cursor);
        scatter_kernel<<<NPTS / 256, 256, 0, stream>>>(om, cursor, sorted, inv, som);
        interp_sorted<<<NPTS * 4 / 256, 256, 0, stream>>>(sorted, som, t0, t1, xt, osort);
        unsort_kernel<<<NPTS / 256, 256, 0, stream>>>(inv, osort, out);
    } else if (ws_size >= xt_bytes) {
        float4* xt = (float4*)ws;
        transpose_fp16<<<NBATCH * PLANE / 256, 256, 0, stream>>>(x, xt);
        interp_direct<<<NPTS * 4 / 256, 256, 0, stream>>>(om, t0, t1, xt, out);
    } else {
        interp_fallback<<<NPTS / 256, 256, 0, stream>>>(om, t0, t1, x, out);
    }
}

// Round 5
// 265.788 us; speedup vs baseline: 1.9565x; 1.5276x over previous
//
#include <hip/hip_runtime.h>
#include <hip/hip_fp16.h>

// KbInterpForw: table-based KB NUFFT interpolation, forward.
// x: (2,16,2,512,512) f32, om: (2,2,262144) f32, tables: (2,6145) f32 each.
// out: (2,16,2,262144) f32.
//
// R5: deterministic atomic-free counting sort (R4's global-atomic scatter was
// 94 us at 0.7% VALUBusy - pure contention). Pipeline:
//   1. transpose grid -> fp16 records (64 B = 16 coils x complex)
//   2. hist2d: per-block LDS histograms -> blockHist[blk][bin]
//   3. scan_bins: per-bin exclusive scan over blocks + binTotal
//   4. scan_kernel: exclusive scan of binTotal -> binBase
//   5. scatter2: LDS local ranks, pos = binBase + blockHist + rank
//   6. interp_sorted: tile-local gathers, fp16 record output (coalesced)
//   7. unsort: permute records to final layout, coalesced writes

#define KLEN      262144      // 2^18
#define GX        512
#define GY        512
#define NCOILS    16
#define NBATCH    2
#define TBL_LEN   6145        // 6*1024+1
#define TBL_CTR   3072
#define PLANE     (GX*GY)
#define NPTS      (NBATCH*KLEN)
#define NBINS     2048        // NBATCH * 32*32 tiles
#define NBLK      256         // sort blocks
#define PPB       2048        // points per sort block (NPTS/NBLK)

typedef _Float16 half2_t __attribute__((ext_vector_type(2)));
struct alignas(16) H8 { half2_t h[4]; };   // 4 coils' (re,im) fp16 = 16 B

// ---------------------------------------------------------------------------
// ws layout (bytes). blockHist/binTotal/binBase alias the osort region: they
// are dead before interp_sorted writes osort.
// ---------------------------------------------------------------------------
#define WS_XT       0                         // 33554432  fp16 grid records
#define WS_OSORT    33554432                  // 33554432  fp16 sorted outputs
#define WS_BHIST    33554432                  //  2097152  u32 [NBLK][NBINS]
#define WS_BTOT     (33554432+2097152)        //     8192  u32 [NBINS]
#define WS_BBASE    (33554432+2097152+8192)   //     8192  u32 [NBINS]
#define WS_SORTED   67108864                  //  2097152  u32 point id per pos
#define WS_INV      69206016                  //  2097152  u32 pos per point id
#define WS_SOM      71303168                  //  4194304  float2 om per pos
#define WS_TOTAL    75497472

__device__ inline int point_bin(float om0, float om1)
{
    const float TWO_PI = 6.2831853071795864769f;
    const float tm0 = (om0 * 512.0f) / TWO_PI;
    const float tm1 = (om1 * 512.0f) / TWO_PI;
    const int cx = ((int)floorf(tm0)) & 511;
    const int cy = ((int)floorf(tm1)) & 511;
    return ((cx >> 4) << 5) | (cy >> 4);      // [0, 1024)
}

// ---------------------------------------------------------------------------
// Transpose+downconvert. Thread handles 4-coil chunk q of 4 consecutive cells;
// q is wave-uniform -> reads are coalesced float4 streams.
// ---------------------------------------------------------------------------
__global__ __launch_bounds__(256) void transpose_fp16(
    const float* __restrict__ x, float4* __restrict__ xt)
{
    const int tid = blockIdx.x * blockDim.x + threadIdx.x;  // [0, NBATCH*PLANE)
    const int b   = tid >> 18;
    const int r   = tid & (PLANE - 1);
    const int q   = r >> 16;            // 4-coil chunk, wave-uniform
    const int cg  = r & 65535;          // cell group (4 cells)
    const int cell = cg * 4;

    const float* xb = x + (size_t)b * NCOILS * 2 * PLANE + cell;

    H8 rec[4];
#pragma unroll
    for (int cc = 0; cc < 4; ++cc) {
        const int c = q * 4 + cc;
        const float4 r4 = *(const float4*)(xb + (size_t)(2 * c)     * PLANE);
        const float4 i4 = *(const float4*)(xb + (size_t)(2 * c + 1) * PLANE);
        rec[0].h[cc] = half2_t{(_Float16)r4.x, (_Float16)i4.x};
        rec[1].h[cc] = half2_t{(_Float16)r4.y, (_Float16)i4.y};
        rec[2].h[cc] = half2_t{(_Float16)r4.z, (_Float16)i4.z};
        rec[3].h[cc] = half2_t{(_Float16)r4.w, (_Float16)i4.w};
    }
#pragma unroll
    for (int i = 0; i < 4; ++i) {
        xt[(size_t)(b * PLANE + cell + i) * 4 + q] = *(const float4*)&rec[i];
    }
}

// ---------------------------------------------------------------------------
// Sort pass 1: per-block LDS histogram. Block blk owns points
// id = blk*PPB + i*256 + t (coalesced om reads). LDS atomics only.
// ---------------------------------------------------------------------------
__global__ __launch_bounds__(256) void hist2d(
    const float* __restrict__ om, unsigned* __restrict__ blockHist)
{
    __shared__ unsigned h[NBINS];
    const int t = threadIdx.x, blk = blockIdx.x;
#pragma unroll
    for (int i = 0; i < NBINS / 256; ++i) h[t + i * 256] = 0u;
    __syncthreads();
#pragma unroll
    for (int i = 0; i < PPB / 256; ++i) {
        const int id = blk * PPB + i * 256 + t;
        const int b = id >> 18, m = id & (KLEN - 1);
        const float om0 = om[(size_t)(b * 2 + 0) * KLEN + m];
        const float om1 = om[(size_t)(b * 2 + 1) * KLEN + m];
        const int g = (b << 10) | point_bin(om0, om1);
        atomicAdd(&h[g], 1u);
    }
    __syncthreads();
#pragma unroll
    for (int i = 0; i < NBINS / 256; ++i) {
        const int bin = t + i * 256;
        blockHist[(size_t)blk * NBINS + bin] = h[bin];   // coalesced
    }
}

// ---------------------------------------------------------------------------
// Sort pass 2: per-bin exclusive scan over the NBLK block counts (in place),
// plus per-bin total. One workgroup per bin; t indexes blk (NBLK==256).
// ---------------------------------------------------------------------------
__global__ __launch_bounds__(256) void scan_bins(
    unsigned* __restrict__ blockHist, unsigned* __restrict__ binTotal)
{
    __shared__ unsigned partial[256];
    const int bin = blockIdx.x;
    const int t = threadIdx.x;
    const unsigned v = blockHist[(size_t)t * NBINS + bin];
    partial[t] = v;
    __syncthreads();
    for (int d = 1; d < 256; d <<= 1) {
        unsigned x = (t >= d) ? partial[t - d] : 0u;
        __syncthreads();
        partial[t] += x;
        __syncthreads();
    }
    blockHist[(size_t)t * NBINS + bin] = partial[t] - v;  // exclusive
    if (t == 255) binTotal[bin] = partial[255];
}

// ---------------------------------------------------------------------------
// Sort pass 3: single-block exclusive scan of the 2048 bin totals.
// ---------------------------------------------------------------------------
__global__ __launch_bounds__(256) void scan_kernel(
    const unsigned* __restrict__ hist, unsigned* __restrict__ cursor)
{
    __shared__ unsigned partial[256];
    const int t = threadIdx.x;
    unsigned v[8];
    unsigned s = 0;
#pragma unroll
    for (int i = 0; i < 8; ++i) { v[i] = hist[t * 8 + i]; s += v[i]; }
    partial[t] = s;
    __syncthreads();
    for (int d = 1; d < 256; d <<= 1) {
        unsigned x = (t >= d) ? partial[t - d] : 0u;
        __syncthreads();
        partial[t] += x;
        __syncthreads();
    }
    unsigned base = (t > 0) ? partial[t - 1] : 0u;   // exclusive
#pragma unroll
    for (int i = 0; i < 8; ++i) { cursor[t * 8 + i] = base; base += v[i]; }
}

// ---------------------------------------------------------------------------
// Sort pass 4: final positions. LDS atomics give local rank within
// (block, bin); global position is deterministic offsets + rank.
// ---------------------------------------------------------------------------
__global__ __launch_bounds__(256) void scatter2(
    const float*    __restrict__ om,
    const unsigned* __restrict__ blockHist,
    const unsigned* __restrict__ binBase,
    unsigned* __restrict__ sorted, unsigned* __restrict__ inv,
    float2* __restrict__ som)
{
    __shared__ unsigned h[NBINS];
    const int t = threadIdx.x, blk = blockIdx.x;
#pragma unroll
    for (int i = 0; i < NBINS / 256; ++i) h[t + i * 256] = 0u;
    __syncthreads();
#pragma unroll
    for (int i = 0; i < PPB / 256; ++i) {
        const int id = blk * PPB + i * 256 + t;
        const int b = id >> 18, m = id & (KLEN - 1);
        const float om0 = om[(size_t)(b * 2 + 0) * KLEN + m];
        const float om1 = om[(size_t)(b * 2 + 1) * KLEN + m];
        const int g = (b << 10) | point_bin(om0, om1);
        const unsigned r = atomicAdd(&h[g], 1u);
        const unsigned pos = binBase[g] + blockHist[(size_t)blk * NBINS + g] + r;
        sorted[pos] = (unsigned)id;
        inv[id]     = pos;
        som[pos]    = make_float2(om0, om1);
    }
}

// ---------------------------------------------------------------------------
// Main interp over sorted positions: 4 lanes per point, lane owns 4 coils.
// Gathers are tile-local (16x16 bins -> ~28 KB neighborhood).
// ---------------------------------------------------------------------------
__global__ __launch_bounds__(256) void interp_sorted(
    const unsigned* __restrict__ sorted,
    const float2*   __restrict__ som,
    const float*    __restrict__ t0,
    const float*    __restrict__ t1,
    const float4*   __restrict__ xt,
    float4*         __restrict__ osort)
{
    const int tid  = blockIdx.x * blockDim.x + threadIdx.x;
    const int lane = tid & 3;
    const int pos  = tid >> 2;            // sorted position in [0, NPTS)

    const unsigned id = sorted[pos];
    const int b = (int)(id >> 18);
    const float2 o = som[pos];
    const float om0 = o.x, om1 = o.y;

    const float TWO_PI = 6.2831853071795864769f;
    const float tm0 = (om0 * 512.0f) / TWO_PI;
    const float tm1 = (om1 * 512.0f) / TWO_PI;

    const float koff0 = 1.0f + floorf(tm0 - 3.0f);
    const float koff1 = 1.0f + floorf(tm1 - 3.0f);
    const int   k0    = (int)koff0;
    const int   k1    = (int)koff1;

    float c0r[6], c0i[6], c1r[6], c1i[6];
    int   coff[6];
#pragma unroll
    for (int j = 0; j < 6; ++j) {
        const float g0 = koff0 + (float)j;
        const int   d0 = (int)rintf((tm0 - g0) * 1024.0f) + TBL_CTR;
        c0r[j] = t0[d0];
        c0i[j] = t0[TBL_LEN + d0];
        const float g1 = koff1 + (float)j;
        const int   d1 = (int)rintf((tm1 - g1) * 1024.0f) + TBL_CTR;
        c1r[j] = t1[d1];
        c1i[j] = t1[TBL_LEN + d1];
        coff[j] = ((k1 + j) & 511) << 2;   // chunk offset within row
    }

    const float4* rec = xt + ((size_t)b << 20);   // b * PLANE * 4 chunks
    float acr[4] = {0.f, 0.f, 0.f, 0.f};
    float aci[4] = {0.f, 0.f, 0.f, 0.f};
#pragma unroll
    for (int j0 = 0; j0 < 6; ++j0) {
        const int roff = (k0 + j0) & 511;
        const float4* rowp = rec + ((size_t)roff << 11) + lane;  // *512*4
        const float ar = c0r[j0], ai = c0i[j0];
#pragma unroll
        for (int j1 = 0; j1 < 6; ++j1) {
            const float br = c1r[j1], bi = c1i[j1];
            const float cr = ar * br - ai * bi;
            const float ci = ar * bi + ai * br;
            const half2_t p1 = {(_Float16)cr, (_Float16)(-ci)}; // real acc
            const half2_t p2 = {(_Float16)ci, (_Float16)cr};    // imag acc
            const float4 raw = rowp[coff[j1]];
            const H8 v = *(const H8*)&raw;
#pragma unroll
            for (int cc = 0; cc < 4; ++cc) {
                acr[cc] = __builtin_amdgcn_fdot2(v.h[cc], p1, acr[cc], false);
                aci[cc] = __builtin_amdgcn_fdot2(v.h[cc], p2, aci[cc], false);
            }
        }
    }

    // phase twist: exp(i * (om0+om1)*128)
    const float ph = om0 * 128.0f + om1 * 128.0f;
    const float s = sinf(ph), c = cosf(ph);

    H8 outrec;
#pragma unroll
    for (int cc = 0; cc < 4; ++cc) {
        const float yr = acr[cc] * c - aci[cc] * s;
        const float yi = acr[cc] * s + aci[cc] * c;
        outrec.h[cc] = half2_t{(_Float16)yr, (_Float16)yi};
    }
    osort[(size_t)pos * 4 + lane] = *(const float4*)&outrec;   // coalesced
}

// ---------------------------------------------------------------------------
// Unsort: thread per point id; gather 64 B record from osort, store coalesced
// into final (b,c,ri,m) layout.
// ---------------------------------------------------------------------------
__global__ __launch_bounds__(256) void unsort_kernel(
    const unsigned* __restrict__ inv,
    const float4*   __restrict__ osort,
    float*          __restrict__ out)
{
    const int id = blockIdx.x * blockDim.x + threadIdx.x;   // [0, NPTS)
    const int b = id >> 18, m = id & (KLEN - 1);
    const unsigned pos = inv[id];
    const float4* rp = osort + (size_t)pos * 4;

    float4 raw[4];
#pragma unroll
    for (int q = 0; q < 4; ++q) raw[q] = rp[q];

    float* ob = out + (size_t)b * NCOILS * 2 * KLEN + m;
#pragma unroll
    for (int q = 0; q < 4; ++q) {
        const H8 v = *(const H8*)&raw[q];
#pragma unroll
        for (int cc = 0; cc < 4; ++cc) {
            const int coil = q * 4 + cc;
            ob[(size_t)(2 * coil)     * KLEN] = (float)v.h[cc].x;
            ob[(size_t)(2 * coil + 1) * KLEN] = (float)v.h[cc].y;
        }
    }
}

// ---------------------------------------------------------------------------
// Middle path (ws >= xt only): direct-order interp.
// ---------------------------------------------------------------------------
__global__ __launch_bounds__(256) void interp_direct(
    const float*  __restrict__ om,
    const float*  __restrict__ t0,
    const float*  __restrict__ t1,
    const float4* __restrict__ xt,
    float*        __restrict__ out)
{
    const int tid  = blockIdx.x * blockDim.x + threadIdx.x;
    const int lane = tid & 3;
    const int p    = tid >> 2;
    const int b    = p >> 18;
    const int m    = p & (KLEN - 1);

    const float om0 = om[(size_t)(b * 2 + 0) * KLEN + m];
    const float om1 = om[(size_t)(b * 2 + 1) * KLEN + m];

    const float TWO_PI = 6.2831853071795864769f;
    const float tm0 = (om0 * 512.0f) / TWO_PI;
    const float tm1 = (om1 * 512.0f) / TWO_PI;
    const float koff0 = 1.0f + floorf(tm0 - 3.0f);
    const float koff1 = 1.0f + floorf(tm1 - 3.0f);
    const int k0 = (int)koff0, k1 = (int)koff1;

    float c0r[6], c0i[6], c1r[6], c1i[6];
    int coff[6];
#pragma unroll
    for (int j = 0; j < 6; ++j) {
        const float g0 = koff0 + (float)j;
        const int d0 = (int)rintf((tm0 - g0) * 1024.0f) + TBL_CTR;
        c0r[j] = t0[d0];
        c0i[j] = t0[TBL_LEN + d0];
        const float g1 = koff1 + (float)j;
        const int d1 = (int)rintf((tm1 - g1) * 1024.0f) + TBL_CTR;
        c1r[j] = t1[d1];
        c1i[j] = t1[TBL_LEN + d1];
        coff[j] = ((k1 + j) & 511) << 2;
    }

    const float4* rec = xt + ((size_t)b << 20);
    float acr[4] = {0.f, 0.f, 0.f, 0.f};
    float aci[4] = {0.f, 0.f, 0.f, 0.f};
#pragma unroll
    for (int j0 = 0; j0 < 6; ++j0) {
        const int roff = (k0 + j0) & 511;
        const float4* rowp = rec + ((size_t)roff << 11) + lane;
        const float ar = c0r[j0], ai = c0i[j0];
#pragma unroll
        for (int j1 = 0; j1 < 6; ++j1) {
            const float br = c1r[j1], bi = c1i[j1];
            const float cr = ar * br - ai * bi;
            const float ci = ar * bi + ai * br;
            const half2_t p1 = {(_Float16)cr, (_Float16)(-ci)};
            const half2_t p2 = {(_Float16)ci, (_Float16)cr};
            const float4 raw = rowp[coff[j1]];
            const H8 v = *(const H8*)&raw;
#pragma unroll
            for (int cc = 0; cc < 4; ++cc) {
                acr[cc] = __builtin_amdgcn_fdot2(v.h[cc], p1, acr[cc], false);
                aci[cc] = __builtin_amdgcn_fdot2(v.h[cc], p2, aci[cc], false);
            }
        }
    }

    const float ph = om0 * 128.0f + om1 * 128.0f;
    const float s = sinf(ph), c = cosf(ph);
#pragma unroll
    for (int cc = 0; cc < 4; ++cc) {
        const float yr = acr[cc] * c - aci[cc] * s;
        const float yi = acr[cc] * s + aci[cc] * c;
        const int coil = lane * 4 + cc;
        const size_t ob = ((size_t)(b * NCOILS + coil) * 2) * KLEN + m;
        out[ob]        = yr;
        out[ob + KLEN] = yi;
    }
}

// ---------------------------------------------------------------------------
// Fallback (tiny ws): one thread per point, original layout.
// ---------------------------------------------------------------------------
__global__ __launch_bounds__(256) void interp_fallback(
    const float* __restrict__ om,
    const float* __restrict__ t0,
    const float* __restrict__ t1,
    const float* __restrict__ x,
    float*       __restrict__ out)
{
    const int p = blockIdx.x * blockDim.x + threadIdx.x;
    const int b = p >> 18;
    const int m = p & (KLEN - 1);

    const float om0 = om[(size_t)(b * 2 + 0) * KLEN + m];
    const float om1 = om[(size_t)(b * 2 + 1) * KLEN + m];
    const float TWO_PI = 6.2831853071795864769f;
    const float tm0 = (om0 * 512.0f) / TWO_PI;
    const float tm1 = (om1 * 512.0f) / TWO_PI;
    const float koff0 = 1.0f + floorf(tm0 - 3.0f);
    const float koff1 = 1.0f + floorf(tm1 - 3.0f);
    const int k0 = (int)koff0, k1 = (int)koff1;

    float c0r[6], c0i[6], c1r[6], c1i[6];
    int roff[6], coff[6];
#pragma unroll
    for (int j = 0; j < 6; ++j) {
        const float g0 = koff0 + (float)j;
        const int d0 = (int)rintf((tm0 - g0) * 1024.0f) + TBL_CTR;
        c0r[j] = t0[d0];
        c0i[j] = t0[TBL_LEN + d0];
        const float g1 = koff1 + (float)j;
        const int d1 = (int)rintf((tm1 - g1) * 1024.0f) + TBL_CTR;
        c1r[j] = t1[d1];
        c1i[j] = t1[TBL_LEN + d1];
        roff[j] = (k0 + j) & 511;
        coff[j] = (k1 + j) & 511;
    }

    float accr[NCOILS], acci[NCOILS];
#pragma unroll
    for (int c = 0; c < NCOILS; ++c) { accr[c] = 0.f; acci[c] = 0.f; }

    const float* xb = x + (size_t)b * NCOILS * 2 * PLANE;
#pragma unroll
    for (int j0 = 0; j0 < 6; ++j0) {
        const float ar = c0r[j0], ai = c0i[j0];
        const int rb = roff[j0] * GY;
#pragma unroll
        for (int j1 = 0; j1 < 6; ++j1) {
            const float br = c1r[j1], bi = c1i[j1];
            const float cr = ar * br - ai * bi;
            const float ci = ar * bi + ai * br;
            const int ai_idx = rb + coff[j1];
#pragma unroll
            for (int c = 0; c < NCOILS; ++c) {
                const float dr = xb[(size_t)c * (2 * PLANE) + ai_idx];
                const float di = xb[(size_t)c * (2 * PLANE) + PLANE + ai_idx];
                accr[c] += cr * dr - ci * di;
                acci[c] += cr * di + ci * dr;
            }
        }
    }

    const float ph = om0 * 128.0f + om1 * 128.0f;
    const float s = sinf(ph), c = cosf(ph);
#pragma unroll
    for (int cc = 0; cc < NCOILS; ++cc) {
        const float yr = accr[cc] * c - acci[cc] * s;
        const float yi = accr[cc] * s + acci[cc] * c;
        size_t ob = ((size_t)(b * NCOILS + cc) * 2) * KLEN + m;
        out[ob]        = yr;
        out[ob + KLEN] = yi;
    }
}

extern "C" void kernel_launch(void* const* d_in, const int* in_sizes, int n_in,
                              void* d_out, int out_size, void* d_ws, size_t ws_size,
                              hipStream_t stream)
{
    const float* x  = (const float*)d_in[0];
    const float* om = (const float*)d_in[1];
    const float* t0 = (const float*)d_in[2];
    const float* t1 = (const float*)d_in[3];
    float* out = (float*)d_out;

    char* ws = (char*)d_ws;
    const size_t xt_bytes = (size_t)NBATCH * PLANE * NCOILS * 2 * sizeof(__half);

    if (ws_size >= (size_t)WS_TOTAL) {
        float4*   xt     = (float4*)(ws + WS_XT);
        float4*   osort  = (float4*)(ws + WS_OSORT);
        unsigned* bhist  = (unsigned*)(ws + WS_BHIST);
        unsigned* btot   = (unsigned*)(ws + WS_BTOT);
        unsigned* bbase  = (unsigned*)(ws + WS_BBASE);
        unsigned* sorted = (unsigned*)(ws + WS_SORTED);
        unsigned* inv    = (unsigned*)(ws + WS_INV);
        float2*   som    = (float2*)(ws + WS_SOM);

        transpose_fp16<<<NBATCH * PLANE / 256, 256, 0, stream>>>(x, xt);
        hist2d<<<NBLK, 256, 0, stream>>>(om, bhist);
        scan_bins<<<NBINS, 256, 0, stream>>>(bhist, btot);
        scan_kernel<<<1, 256, 0, stream>>>(btot, bbase);
        scatter2<<<NBLK, 256, 0, stream>>>(om, bhist, bbase, sorted, inv, som);
        interp_sorted<<<NPTS * 4 / 256, 256, 0, stream>>>(sorted, som, t0, t1, xt, osort);
        unsort_kernel<<<NPTS / 256, 256, 0, stream>>>(inv, osort, out);
    } else if (ws_size >= xt_bytes) {
        float4* xt = (float4*)ws;
        transpose_fp16<<<NBATCH * PLANE / 256, 256, 0, stream>>>(x, xt);
        interp_direct<<<NPTS * 4 / 256, 256, 0, stream>>>(om, t0, t1, xt, out);
    } else {
        interp_fallback<<<NPTS / 256, 256, 0, stream>>>(om, t0, t1, x, out);
    }
}

// Round 6
// 246.400 us; speedup vs baseline: 2.1105x; 1.0787x over previous
//
#include <hip/hip_runtime.h>
#include <hip/hip_fp16.h>

// KbInterpForw: table-based KB NUFFT interpolation, forward.
// x: (2,16,2,512,512) f32, om: (2,2,262144) f32, tables: (2,6145) f32 each.
// out: (2,16,2,262144) f32.
//
// R6 (on top of R5's deterministic tile-sort pipeline):
//  - blockHist is now BIN-MAJOR [bin][blk] so scan_bins is fully coalesced
//    (R5 had 8 KB lane stride -> 64 transactions/wave-load, twice).
//  - transpose_fp16 stages through LDS: coalesced 1 KB global reads AND
//    coalesced 16 B record stores (R5 stores were 256 B-strided, 4x lines).
//  - `sorted` array dropped: bins are batch-major and each batch has exactly
//    KLEN points, so batch b == pos >> 18 inside interp_sorted.

#define KLEN      262144      // 2^18
#define GX        512
#define GY        512
#define NCOILS    16
#define NBATCH    2
#define TBL_LEN   6145        // 6*1024+1
#define TBL_CTR   3072
#define PLANE     (GX*GY)
#define NPTS      (NBATCH*KLEN)
#define NBINS     2048        // NBATCH * 32*32 tiles
#define NBLK      256         // sort blocks
#define PPB       2048        // points per sort block (NPTS/NBLK)

typedef _Float16 half2_t __attribute__((ext_vector_type(2)));
struct alignas(16) H8 { half2_t h[4]; };   // 4 coils' (re,im) fp16 = 16 B

// ---------------------------------------------------------------------------
// ws layout (bytes). blockHist/binTotal/binBase alias the osort region: they
// are dead before interp_sorted writes osort.
// ---------------------------------------------------------------------------
#define WS_XT       0                         // 33554432  fp16 grid records
#define WS_OSORT    33554432                  // 33554432  fp16 sorted outputs
#define WS_BHIST    33554432                  //  2097152  u32 [NBINS][NBLK]
#define WS_BTOT     (33554432+2097152)        //     8192  u32 [NBINS]
#define WS_BBASE    (33554432+2097152+8192)   //     8192  u32 [NBINS]
#define WS_INV      69206016                  //  2097152  u32 pos per point id
#define WS_SOM      71303168                  //  4194304  float2 om per pos
#define WS_TOTAL    75497472

__device__ inline int point_bin(float om0, float om1)
{
    const float TWO_PI = 6.2831853071795864769f;
    const float tm0 = (om0 * 512.0f) / TWO_PI;
    const float tm1 = (om1 * 512.0f) / TWO_PI;
    const int cx = ((int)floorf(tm0)) & 511;
    const int cy = ((int)floorf(tm1)) & 511;
    return ((cx >> 4) << 5) | (cy >> 4);      // [0, 1024)
}

// ---------------------------------------------------------------------------
// Transpose+downconvert via LDS. Block handles 256 consecutive cells.
// Phase 1: 8 iters, each wave reads one plane's 1 KB segment (float4/lane).
// Phase 2: thread t writes chunk (cell = c>>2, q = c&3) -> consecutive 16 B
// stores, fully coalesced.
// ---------------------------------------------------------------------------
__global__ __launch_bounds__(256) void transpose_fp16(
    const float* __restrict__ x, float4* __restrict__ xt)
{
    __shared__ float s[32][260];   // [plane][cell], pad 260 (16B-aligned rows)
    const int blk   = blockIdx.x;            // [0, NBATCH*PLANE/256)
    const int base  = blk * 256;
    const int b     = base >> 18;
    const int cell0 = base & (PLANE - 1);
    const int t     = threadIdx.x;

    const float* xb = x + (size_t)b * 32 * PLANE + cell0;
#pragma unroll
    for (int i = 0; i < 8; ++i) {
        const int fidx = i * 256 + t;        // [0, 2048)
        const int pl = fidx >> 6;            // wave-uniform plane
        const int j  = fidx & 63;
        const float4 v = *(const float4*)(xb + (size_t)pl * PLANE + j * 4);
        *(float4*)&s[pl][j * 4] = v;
    }
    __syncthreads();
#pragma unroll
    for (int i = 0; i < 4; ++i) {
        const int chunk = i * 256 + t;       // [0, 1024)
        const int cell = chunk >> 2, q = chunk & 3;
        H8 rec;
#pragma unroll
        for (int cc = 0; cc < 4; ++cc) {
            const int c = q * 4 + cc;
            rec.h[cc] = half2_t{(_Float16)s[2 * c][cell],
                                (_Float16)s[2 * c + 1][cell]};
        }
        xt[((size_t)b * PLANE + cell0 + cell) * 4 + q] = *(const float4*)&rec;
    }
}

// ---------------------------------------------------------------------------
// Sort pass 1: per-block LDS histogram -> blockHist[bin][blk] (bin-major).
// ---------------------------------------------------------------------------
__global__ __launch_bounds__(256) void hist2d(
    const float* __restrict__ om, unsigned* __restrict__ blockHist)
{
    __shared__ unsigned h[NBINS];
    const int t = threadIdx.x, blk = blockIdx.x;
#pragma unroll
    for (int i = 0; i < NBINS / 256; ++i) h[t + i * 256] = 0u;
    __syncthreads();
#pragma unroll
    for (int i = 0; i < PPB / 256; ++i) {
        const int id = blk * PPB + i * 256 + t;
        const int b = id >> 18, m = id & (KLEN - 1);
        const float om0 = om[(size_t)(b * 2 + 0) * KLEN + m];
        const float om1 = om[(size_t)(b * 2 + 1) * KLEN + m];
        const int g = (b << 10) | point_bin(om0, om1);
        atomicAdd(&h[g], 1u);
    }
    __syncthreads();
#pragma unroll
    for (int i = 0; i < NBINS / 256; ++i) {
        const int bin = t + i * 256;
        blockHist[(size_t)bin * NBLK + blk] = h[bin];   // strided once
    }
}

// ---------------------------------------------------------------------------
// Sort pass 2: per-bin exclusive scan over NBLK block counts (coalesced row
// read/write in bin-major layout) + per-bin total.
// ---------------------------------------------------------------------------
__global__ __launch_bounds__(256) void scan_bins(
    unsigned* __restrict__ blockHist, unsigned* __restrict__ binTotal)
{
    __shared__ unsigned partial[256];
    const int bin = blockIdx.x;
    const int t = threadIdx.x;
    const unsigned v = blockHist[(size_t)bin * NBLK + t];   // coalesced 1 KB
    partial[t] = v;
    __syncthreads();
    for (int d = 1; d < 256; d <<= 1) {
        unsigned x = (t >= d) ? partial[t - d] : 0u;
        __syncthreads();
        partial[t] += x;
        __syncthreads();
    }
    blockHist[(size_t)bin * NBLK + t] = partial[t] - v;     // exclusive
    if (t == 255) binTotal[bin] = partial[255];
}

// ---------------------------------------------------------------------------
// Sort pass 3: single-block exclusive scan of the 2048 bin totals.
// ---------------------------------------------------------------------------
__global__ __launch_bounds__(256) void scan_kernel(
    const unsigned* __restrict__ hist, unsigned* __restrict__ cursor)
{
    __shared__ unsigned partial[256];
    const int t = threadIdx.x;
    unsigned v[8];
    unsigned s = 0;
#pragma unroll
    for (int i = 0; i < 8; ++i) { v[i] = hist[t * 8 + i]; s += v[i]; }
    partial[t] = s;
    __syncthreads();
    for (int d = 1; d < 256; d <<= 1) {
        unsigned x = (t >= d) ? partial[t - d] : 0u;
        __syncthreads();
        partial[t] += x;
        __syncthreads();
    }
    unsigned base = (t > 0) ? partial[t - 1] : 0u;   // exclusive
#pragma unroll
    for (int i = 0; i < 8; ++i) { cursor[t * 8 + i] = base; base += v[i]; }
}

// ---------------------------------------------------------------------------
// Sort pass 4: final positions. LDS atomics give local rank within
// (block, bin); position = binBase + blockHist + rank. No `sorted` array:
// batch is recoverable from pos (bins are batch-major, KLEN pts per batch).
// ---------------------------------------------------------------------------
__global__ __launch_bounds__(256) void scatter2(
    const float*    __restrict__ om,
    const unsigned* __restrict__ blockHist,
    const unsigned* __restrict__ binBase,
    unsigned* __restrict__ inv,
    float2* __restrict__ som)
{
    __shared__ unsigned h[NBINS];
    const int t = threadIdx.x, blk = blockIdx.x;
#pragma unroll
    for (int i = 0; i < NBINS / 256; ++i) h[t + i * 256] = 0u;
    __syncthreads();
#pragma unroll
    for (int i = 0; i < PPB / 256; ++i) {
        const int id = blk * PPB + i * 256 + t;
        const int b = id >> 18, m = id & (KLEN - 1);
        const float om0 = om[(size_t)(b * 2 + 0) * KLEN + m];
        const float om1 = om[(size_t)(b * 2 + 1) * KLEN + m];
        const int g = (b << 10) | point_bin(om0, om1);
        const unsigned r = atomicAdd(&h[g], 1u);
        const unsigned pos = binBase[g] + blockHist[(size_t)g * NBLK + blk] + r;
        inv[id]  = pos;
        som[pos] = make_float2(om0, om1);
    }
}

// ---------------------------------------------------------------------------
// Main interp over sorted positions: 4 lanes per point, lane owns 4 coils.
// Gathers are tile-local (16x16 bins -> ~28 KB neighborhood).
// ---------------------------------------------------------------------------
__global__ __launch_bounds__(256) void interp_sorted(
    const float2*   __restrict__ som,
    const float*    __restrict__ t0,
    const float*    __restrict__ t1,
    const float4*   __restrict__ xt,
    float4*         __restrict__ osort)
{
    const int tid  = blockIdx.x * blockDim.x + threadIdx.x;
    const int lane = tid & 3;
    const int pos  = tid >> 2;            // sorted position in [0, NPTS)
    const int b    = pos >> 18;           // batch-major bins, KLEN pts/batch

    const float2 o = som[pos];
    const float om0 = o.x, om1 = o.y;

    const float TWO_PI = 6.2831853071795864769f;
    const float tm0 = (om0 * 512.0f) / TWO_PI;
    const float tm1 = (om1 * 512.0f) / TWO_PI;

    const float koff0 = 1.0f + floorf(tm0 - 3.0f);
    const float koff1 = 1.0f + floorf(tm1 - 3.0f);
    const int   k0    = (int)koff0;
    const int   k1    = (int)koff1;

    float c0r[6], c0i[6], c1r[6], c1i[6];
    int   coff[6];
#pragma unroll
    for (int j = 0; j < 6; ++j) {
        const float g0 = koff0 + (float)j;
        const int   d0 = (int)rintf((tm0 - g0) * 1024.0f) + TBL_CTR;
        c0r[j] = t0[d0];
        c0i[j] = t0[TBL_LEN + d0];
        const float g1 = koff1 + (float)j;
        const int   d1 = (int)rintf((tm1 - g1) * 1024.0f) + TBL_CTR;
        c1r[j] = t1[d1];
        c1i[j] = t1[TBL_LEN + d1];
        coff[j] = ((k1 + j) & 511) << 2;   // chunk offset within row
    }

    const float4* rec = xt + ((size_t)b << 20);   // b * PLANE * 4 chunks
    float acr[4] = {0.f, 0.f, 0.f, 0.f};
    float aci[4] = {0.f, 0.f, 0.f, 0.f};
#pragma unroll
    for (int j0 = 0; j0 < 6; ++j0) {
        const int roff = (k0 + j0) & 511;
        const float4* rowp = rec + ((size_t)roff << 11) + lane;  // *512*4
        const float ar = c0r[j0], ai = c0i[j0];
#pragma unroll
        for (int j1 = 0; j1 < 6; ++j1) {
            const float br = c1r[j1], bi = c1i[j1];
            const float cr = ar * br - ai * bi;
            const float ci = ar * bi + ai * br;
            const half2_t p1 = {(_Float16)cr, (_Float16)(-ci)}; // real acc
            const half2_t p2 = {(_Float16)ci, (_Float16)cr};    // imag acc
            const float4 raw = rowp[coff[j1]];
            const H8 v = *(const H8*)&raw;
#pragma unroll
            for (int cc = 0; cc < 4; ++cc) {
                acr[cc] = __builtin_amdgcn_fdot2(v.h[cc], p1, acr[cc], false);
                aci[cc] = __builtin_amdgcn_fdot2(v.h[cc], p2, aci[cc], false);
            }
        }
    }

    // phase twist: exp(i * (om0+om1)*128)
    const float ph = om0 * 128.0f + om1 * 128.0f;
    const float s = sinf(ph), c = cosf(ph);

    H8 outrec;
#pragma unroll
    for (int cc = 0; cc < 4; ++cc) {
        const float yr = acr[cc] * c - aci[cc] * s;
        const float yi = acr[cc] * s + aci[cc] * c;
        outrec.h[cc] = half2_t{(_Float16)yr, (_Float16)yi};
    }
    osort[(size_t)pos * 4 + lane] = *(const float4*)&outrec;   // coalesced
}

// ---------------------------------------------------------------------------
// Unsort: thread per point id; gather 64 B record from osort, store coalesced
// into final (b,c,ri,m) layout.
// ---------------------------------------------------------------------------
__global__ __launch_bounds__(256) void unsort_kernel(
    const unsigned* __restrict__ inv,
    const float4*   __restrict__ osort,
    float*          __restrict__ out)
{
    const int id = blockIdx.x * blockDim.x + threadIdx.x;   // [0, NPTS)
    const int b = id >> 18, m = id & (KLEN - 1);
    const unsigned pos = inv[id];
    const float4* rp = osort + (size_t)pos * 4;

    float4 raw[4];
#pragma unroll
    for (int q = 0; q < 4; ++q) raw[q] = rp[q];

    float* ob = out + (size_t)b * NCOILS * 2 * KLEN + m;
#pragma unroll
    for (int q = 0; q < 4; ++q) {
        const H8 v = *(const H8*)&raw[q];
#pragma unroll
        for (int cc = 0; cc < 4; ++cc) {
            const int coil = q * 4 + cc;
            ob[(size_t)(2 * coil)     * KLEN] = (float)v.h[cc].x;
            ob[(size_t)(2 * coil + 1) * KLEN] = (float)v.h[cc].y;
        }
    }
}

// ---------------------------------------------------------------------------
// Middle path (ws >= xt only): direct-order interp.
// ---------------------------------------------------------------------------
__global__ __launch_bounds__(256) void interp_direct(
    const float*  __restrict__ om,
    const float*  __restrict__ t0,
    const float*  __restrict__ t1,
    const float4* __restrict__ xt,
    float*        __restrict__ out)
{
    const int tid  = blockIdx.x * blockDim.x + threadIdx.x;
    const int lane = tid & 3;
    const int p    = tid >> 2;
    const int b    = p >> 18;
    const int m    = p & (KLEN - 1);

    const float om0 = om[(size_t)(b * 2 + 0) * KLEN + m];
    const float om1 = om[(size_t)(b * 2 + 1) * KLEN + m];

    const float TWO_PI = 6.2831853071795864769f;
    const float tm0 = (om0 * 512.0f) / TWO_PI;
    const float tm1 = (om1 * 512.0f) / TWO_PI;
    const float koff0 = 1.0f + floorf(tm0 - 3.0f);
    const float koff1 = 1.0f + floorf(tm1 - 3.0f);
    const int k0 = (int)koff0, k1 = (int)koff1;

    float c0r[6], c0i[6], c1r[6], c1i[6];
    int coff[6];
#pragma unroll
    for (int j = 0; j < 6; ++j) {
        const float g0 = koff0 + (float)j;
        const int d0 = (int)rintf((tm0 - g0) * 1024.0f) + TBL_CTR;
        c0r[j] = t0[d0];
        c0i[j] = t0[TBL_LEN + d0];
        const float g1 = koff1 + (float)j;
        const int d1 = (int)rintf((tm1 - g1) * 1024.0f) + TBL_CTR;
        c1r[j] = t1[d1];
        c1i[j] = t1[TBL_LEN + d1];
        coff[j] = ((k1 + j) & 511) << 2;
    }

    const float4* rec = xt + ((size_t)b << 20);
    float acr[4] = {0.f, 0.f, 0.f, 0.f};
    float aci[4] = {0.f, 0.f, 0.f, 0.f};
#pragma unroll
    for (int j0 = 0; j0 < 6; ++j0) {
        const int roff = (k0 + j0) & 511;
        const float4* rowp = rec + ((size_t)roff << 11) + lane;
        const float ar = c0r[j0], ai = c0i[j0];
#pragma unroll
        for (int j1 = 0; j1 < 6; ++j1) {
            const float br = c1r[j1], bi = c1i[j1];
            const float cr = ar * br - ai * bi;
            const float ci = ar * bi + ai * br;
            const half2_t p1 = {(_Float16)cr, (_Float16)(-ci)};
            const half2_t p2 = {(_Float16)ci, (_Float16)cr};
            const float4 raw = rowp[coff[j1]];
            const H8 v = *(const H8*)&raw;
#pragma unroll
            for (int cc = 0; cc < 4; ++cc) {
                acr[cc] = __builtin_amdgcn_fdot2(v.h[cc], p1, acr[cc], false);
                aci[cc] = __builtin_amdgcn_fdot2(v.h[cc], p2, aci[cc], false);
            }
        }
    }

    const float ph = om0 * 128.0f + om1 * 128.0f;
    const float s = sinf(ph), c = cosf(ph);
#pragma unroll
    for (int cc = 0; cc < 4; ++cc) {
        const float yr = acr[cc] * c - aci[cc] * s;
        const float yi = acr[cc] * s + aci[cc] * c;
        const int coil = lane * 4 + cc;
        const size_t ob = ((size_t)(b * NCOILS + coil) * 2) * KLEN + m;
        out[ob]        = yr;
        out[ob + KLEN] = yi;
    }
}

// ---------------------------------------------------------------------------
// Fallback (tiny ws): one thread per point, original layout.
// ---------------------------------------------------------------------------
__global__ __launch_bounds__(256) void interp_fallback(
    const float* __restrict__ om,
    const float* __restrict__ t0,
    const float* __restrict__ t1,
    const float* __restrict__ x,
    float*       __restrict__ out)
{
    const int p = blockIdx.x * blockDim.x + threadIdx.x;
    const int b = p >> 18;
    const int m = p & (KLEN - 1);

    const float om0 = om[(size_t)(b * 2 + 0) * KLEN + m];
    const float om1 = om[(size_t)(b * 2 + 1) * KLEN + m];
    const float TWO_PI = 6.2831853071795864769f;
    const float tm0 = (om0 * 512.0f) / TWO_PI;
    const float tm1 = (om1 * 512.0f) / TWO_PI;
    const float koff0 = 1.0f + floorf(tm0 - 3.0f);
    const float koff1 = 1.0f + floorf(tm1 - 3.0f);
    const int k0 = (int)koff0, k1 = (int)koff1;

    float c0r[6], c0i[6], c1r[6], c1i[6];
    int roff[6], coff[6];
#pragma unroll
    for (int j = 0; j < 6; ++j) {
        const float g0 = koff0 + (float)j;
        const int d0 = (int)rintf((tm0 - g0) * 1024.0f) + TBL_CTR;
        c0r[j] = t0[d0];
        c0i[j] = t0[TBL_LEN + d0];
        const float g1 = koff1 + (float)j;
        const int d1 = (int)rintf((tm1 - g1) * 1024.0f) + TBL_CTR;
        c1r[j] = t1[d1];
        c1i[j] = t1[TBL_LEN + d1];
        roff[j] = (k0 + j) & 511;
        coff[j] = (k1 + j) & 511;
    }

    float accr[NCOILS], acci[NCOILS];
#pragma unroll
    for (int c = 0; c < NCOILS; ++c) { accr[c] = 0.f; acci[c] = 0.f; }

    const float* xb = x + (size_t)b * NCOILS * 2 * PLANE;
#pragma unroll
    for (int j0 = 0; j0 < 6; ++j0) {
        const float ar = c0r[j0], ai = c0i[j0];
        const int rb = roff[j0] * GY;
#pragma unroll
        for (int j1 = 0; j1 < 6; ++j1) {
            const float br = c1r[j1], bi = c1i[j1];
            const float cr = ar * br - ai * bi;
            const float ci = ar * bi + ai * br;
            const int ai_idx = rb + coff[j1];
#pragma unroll
            for (int c = 0; c < NCOILS; ++c) {
                const float dr = xb[(size_t)c * (2 * PLANE) + ai_idx];
                const float di = xb[(size_t)c * (2 * PLANE) + PLANE + ai_idx];
                accr[c] += cr * dr - ci * di;
                acci[c] += cr * di + ci * dr;
            }
        }
    }

    const float ph = om0 * 128.0f + om1 * 128.0f;
    const float s = sinf(ph), c = cosf(ph);
#pragma unroll
    for (int cc = 0; cc < NCOILS; ++cc) {
        const float yr = accr[cc] * c - acci[cc] * s;
        const float yi = accr[cc] * s + acci[cc] * c;
        size_t ob = ((size_t)(b * NCOILS + cc) * 2) * KLEN + m;
        out[ob]        = yr;
        out[ob + KLEN] = yi;
    }
}

extern "C" void kernel_launch(void* const* d_in, const int* in_sizes, int n_in,
                              void* d_out, int out_size, void* d_ws, size_t ws_size,
                              hipStream_t stream)
{
    const float* x  = (const float*)d_in[0];
    const float* om = (const float*)d_in[1];
    const float* t0 = (const float*)d_in[2];
    const float* t1 = (const float*)d_in[3];
    float* out = (float*)d_out;

    char* ws = (char*)d_ws;
    const size_t xt_bytes = (size_t)NBATCH * PLANE * NCOILS * 2 * sizeof(__half);

    if (ws_size >= (size_t)WS_TOTAL) {
        float4*   xt     = (float4*)(ws + WS_XT);
        float4*   osort  = (float4*)(ws + WS_OSORT);
        unsigned* bhist  = (unsigned*)(ws + WS_BHIST);
        unsigned* btot   = (unsigned*)(ws + WS_BTOT);
        unsigned* bbase  = (unsigned*)(ws + WS_BBASE);
        unsigned* inv    = (unsigned*)(ws + WS_INV);
        float2*   som    = (float2*)(ws + WS_SOM);

        transpose_fp16<<<NBATCH * PLANE / 256, 256, 0, stream>>>(x, xt);
        hist2d<<<NBLK, 256, 0, stream>>>(om, bhist);
        scan_bins<<<NBINS, 256, 0, stream>>>(bhist, btot);
        scan_kernel<<<1, 256, 0, stream>>>(btot, bbase);
        scatter2<<<NBLK, 256, 0, stream>>>(om, bhist, bbase, inv, som);
        interp_sorted<<<NPTS * 4 / 256, 256, 0, stream>>>(som, t0, t1, xt, osort);
        unsort_kernel<<<NPTS / 256, 256, 0, stream>>>(inv, osort, out);
    } else if (ws_size >= xt_bytes) {
        float4* xt = (float4*)ws;
        transpose_fp16<<<NBATCH * PLANE / 256, 256, 0, stream>>>(x, xt);
        interp_direct<<<NPTS * 4 / 256, 256, 0, stream>>>(om, t0, t1, xt, out);
    } else {
        interp_fallback<<<NPTS / 256, 256, 0, stream>>>(om, t0, t1, x, out);
    }
}